// Round 6
// baseline (233.237 us; speedup 1.0000x reference)
//
#include <hip/hip_runtime.h>
#include <hip/hip_bf16.h>
#include <hip/hip_fp16.h>

// B=16, N=512, D=512, H=8, DH=64, PD=9, HID=32
#define NN 512
#define HH 8
#define DHH 64

typedef __attribute__((ext_vector_type(8))) short short8v;
typedef __attribute__((ext_vector_type(8))) unsigned short ushort8v;
typedef __attribute__((ext_vector_type(4))) unsigned short ushort4v;
typedef __attribute__((ext_vector_type(4))) float f32x4;
typedef __attribute__((ext_vector_type(8))) _Float16 f16x8;

__device__ __forceinline__ unsigned short f2bf(float x) {
  unsigned u = __builtin_bit_cast(unsigned, x);
  u += 0x7FFFu + ((u >> 16) & 1u);
  return (unsigned short)(u >> 16);
}
__device__ __forceinline__ int swz64(int r, int cb) { return r * 64 + (cb ^ (((r >> 1) & 3) << 4)); }
__device__ __forceinline__ int swz128(int r, int cb) { return r * 128 + (cb ^ ((r & 7) << 4)); }

// ---------------- fp32 -> bf16 elementwise ----------------
__global__ __launch_bounds__(256) void cvt_bf(const float* __restrict__ src,
                                              unsigned short* __restrict__ dst, int n) {
  int i = (blockIdx.x * 256 + threadIdx.x) * 4;
  if (i < n) {
    float4 v = *(const float4*)&src[i];
    ushort4v o;
    o[0] = f2bf(v.x); o[1] = f2bf(v.y); o[2] = f2bf(v.z); o[3] = f2bf(v.w);
    *(ushort4v*)&dst[i] = o;
  }
}

// ---------------- transpose + cvt: src fp32 [R][C] -> dst bf16 [C][R] ----------------
__global__ __launch_bounds__(256) void transpose_cvt(const float* __restrict__ src,
                                                     unsigned short* __restrict__ dst,
                                                     int R, int C) {
  __shared__ float t[32][33];
  const int r0 = blockIdx.x * 32, c0 = blockIdx.y * 32;
  const int rr = threadIdx.x >> 3, c4 = (threadIdx.x & 7) * 4;
  float4 v = *(const float4*)&src[(size_t)(r0 + rr) * C + c0 + c4];
  t[rr][c4 + 0] = v.x; t[rr][c4 + 1] = v.y; t[rr][c4 + 2] = v.z; t[rr][c4 + 3] = v.w;
  __syncthreads();
  ushort4v o;
#pragma unroll
  for (int e = 0; e < 4; ++e) o[e] = f2bf(t[c4 + e][rr]);
  *(ushort4v*)&dst[(size_t)(c0 + rr) * R + r0 + c4] = o;
}

// ---------------- shared 128x128 bf16 MFMA GEMM body (BK=32, 4 waves) ----------------
__device__ __forceinline__ void gemm128_body(const unsigned short* __restrict__ A,
                                             const unsigned short* __restrict__ Bt,
                                             int ldk, int m0, int n0,
                                             f32x4 acc[4][4], unsigned char* smem) {
  const int tid = threadIdx.x, lane = tid & 63, wid = tid >> 6;
  const int wm = wid >> 1, wn = wid & 1;
  int aoff[4], boff[4];
#pragma unroll
  for (int i = 0; i < 4; ++i) {
    aoff[i] = swz64(wm * 64 + i * 16 + (lane & 15), (lane >> 4) * 16);
    boff[i] = 8192 + swz64(wn * 64 + i * 16 + (lane & 15), (lane >> 4) * 16);
  }
  for (int k0 = 0; k0 < ldk; k0 += 32) {
#pragma unroll
    for (int p = 0; p < 2; ++p) {
      const int idx = p * 256 + tid;
      const int r = idx >> 2, cg = idx & 3;
      ushort8v av = *(const ushort8v*)&A[(size_t)(m0 + r) * ldk + k0 + cg * 8];
      *(ushort8v*)&smem[swz64(r, cg * 16)] = av;
      ushort8v bv = *(const ushort8v*)&Bt[(size_t)(n0 + r) * ldk + k0 + cg * 8];
      *(ushort8v*)&smem[8192 + swz64(r, cg * 16)] = bv;
    }
    __syncthreads();
    short8v a[4], b[4];
#pragma unroll
    for (int i = 0; i < 4; ++i) {
      a[i] = *(const short8v*)&smem[aoff[i]];
      b[i] = *(const short8v*)&smem[boff[i]];
    }
#pragma unroll
    for (int i = 0; i < 4; ++i)
#pragma unroll
      for (int j = 0; j < 4; ++j)
        acc[i][j] = __builtin_amdgcn_mfma_f32_16x16x32_bf16(a[i], b[j], acc[i][j], 0, 0, 0);
    __syncthreads();
  }
}

// ---------------- QKV GEMM -> q [bh][n][dh], k [bh][n][dh], v TRANSPOSED [bh][dh][n] ----------------
__global__ __launch_bounds__(256) void gemm_qkv(const unsigned short* __restrict__ A,
                                                const unsigned short* __restrict__ Bt,
                                                unsigned short* __restrict__ q,
                                                unsigned short* __restrict__ k,
                                                unsigned short* __restrict__ vt) {
  __shared__ unsigned char smem[16384];
  f32x4 acc[4][4];
  const f32x4 z = {0.f, 0.f, 0.f, 0.f};
#pragma unroll
  for (int i = 0; i < 4; ++i)
#pragma unroll
    for (int j = 0; j < 4; ++j) acc[i][j] = z;
  gemm128_body(A, Bt, 512, blockIdx.x * 128, blockIdx.y * 128, acc, smem);
  const int lane = threadIdx.x & 63, wid = threadIdx.x >> 6;
  const int wm = wid >> 1, wn = wid & 1;
#pragma unroll
  for (int i = 0; i < 4; ++i) {
    const int row0 = blockIdx.x * 128 + wm * 64 + i * 16 + ((lane >> 4) << 2);
#pragma unroll
    for (int j = 0; j < 4; ++j) {
      const int col = blockIdx.y * 128 + wn * 64 + j * 16 + (lane & 15);
      const int part = col >> 9, head = (col >> 6) & 7, dh = col & 63;
      if (part == 2) {
        // V^T: 4 consecutive n -> one 8B store
        const int b_ = row0 >> 9, n_ = row0 & 511;
        ushort4v pk;
#pragma unroll
        for (int rr = 0; rr < 4; ++rr) pk[rr] = f2bf(acc[i][j][rr]);
        *(ushort4v*)&vt[(((b_ * HH + head) * DHH) + dh) * NN + n_] = pk;
      } else {
        unsigned short* dst = (part == 0) ? q : k;
#pragma unroll
        for (int rr = 0; rr < 4; ++rr) {
          const int row = row0 + rr;
          const int b_ = row >> 9, n_ = row & 511;
          dst[(((b_ * HH + head) * NN) + n_) * DHH + dh] = f2bf(acc[i][j][rr]);
        }
      }
    }
  }
}

// ---------------- out GEMM: ao_bf[8192][512] @ WoT[512][512]^T -> fp32 out (masked) ----------------
__global__ __launch_bounds__(256) void gemm_out(const unsigned short* __restrict__ A,
                                                const unsigned short* __restrict__ Bt,
                                                const int* __restrict__ msk,
                                                float* __restrict__ out) {
  __shared__ unsigned char smem[16384];
  f32x4 acc[4][4];
  const f32x4 z = {0.f, 0.f, 0.f, 0.f};
#pragma unroll
  for (int i = 0; i < 4; ++i)
#pragma unroll
    for (int j = 0; j < 4; ++j) acc[i][j] = z;
  gemm128_body(A, Bt, 512, blockIdx.x * 128, blockIdx.y * 128, acc, smem);
  const int lane = threadIdx.x & 63, wid = threadIdx.x >> 6;
  const int wm = wid >> 1, wn = wid & 1;
#pragma unroll
  for (int i = 0; i < 4; ++i) {
    const int row0 = blockIdx.x * 128 + wm * 64 + i * 16 + ((lane >> 4) << 2);
#pragma unroll
    for (int j = 0; j < 4; ++j) {
      const int col = blockIdx.y * 128 + wn * 64 + j * 16 + (lane & 15);
#pragma unroll
      for (int rr = 0; rr < 4; ++rr) {
        const int row = row0 + rr;
        const float mm = (msk[row] != 0) ? 1.f : 0.f;
        out[(size_t)row * 512 + col] = acc[i][j][rr] * mm;
      }
    }
  }
}

// ---------------- FUSED pairwise-bias MLP + flash attention (v3) ----------------
// = round-4 structure (proven numerics) with:
//  (a) bias LDS layout [i][ (j*8+h) ^ ((i>>2)<<1) ]: writer <=2-way, reader <=2-way
//      (round-4 layout was 8-way on writes: head stride 2176B = bank 0);
//  (b) single-buffered bias + 2nd barrier after bias-read (safe: no bias reads after);
//  (c) hbuf aliased into per-wave ps buffer (both wave-local, disjoint phases)
//      -> LDS 73.7KB -> 45KB -> 3 blocks/CU.
__global__ __launch_bounds__(512, 4) void attn_bias_fused(
    const unsigned short* __restrict__ q, const unsigned short* __restrict__ k,
    const unsigned short* __restrict__ vt, const float* __restrict__ vvec,
    const int* __restrict__ tti, const int* __restrict__ msk,
    const float* __restrict__ W1, const float* __restrict__ b1,
    const float* __restrict__ W2, const float* __restrict__ b2,
    unsigned short* __restrict__ ao) {
  __shared__ float4 sv4[NN];
  __shared__ int stt[NN];
  __shared__ float smask[NN];
  __shared__ unsigned short bias_lds[16 * 512];   // 16KB single-buffered, XOR layout
  __shared__ unsigned char wavebuf[HH][2048];     // per-wave: Phase A = hbuf, Phase B = ps
  const int tid = threadIdx.x, lane = tid & 63, w = tid >> 6;
  const int l16 = lane & 15, lg = lane >> 4;
  const int it = blockIdx.x, b_ = blockIdx.y;
  const int i0 = it * 16;
  for (int idx = tid; idx < NN; idx += 512) {
    sv4[idx] = *(const float4*)&vvec[(b_ * NN + idx) * 4];
    stt[idx] = tti[idx];
    smask[idx] = (msk[b_ * NN + idx] != 0) ? 0.f : -1e30f;
  }
  // MLP weight fragments (round-4 proven): W1 B-frag (col=c), W2 B-frag (col=head)
  f16x8 w1f[2], w2f;
#pragma unroll
  for (int t = 0; t < 2; ++t)
#pragma unroll
    for (int e = 0; e < 8; ++e) {
      const int kk = lg * 8 + e;
      w1f[t][e] = (kk < 9) ? (_Float16)W1[kk * 32 + t * 16 + l16] : (_Float16)0.f;
    }
#pragma unroll
  for (int e = 0; e < 8; ++e)
    w2f[e] = (l16 < 8) ? (_Float16)W2[(lg * 8 + e) * 8 + l16] : (_Float16)0.f;
  const float b1v0 = b1[l16], b1v1 = b1[16 + l16];
  const float b2v = (l16 < 8) ? b2[l16] : 0.f;
  // per-head attention state
  const unsigned short* qb = q + ((size_t)(b_ * HH + w) * NN + i0) * DHH;
  const unsigned short* kb = k + (size_t)(b_ * HH + w) * NN * DHH;
  const unsigned short* vtb = vt + (size_t)(b_ * HH + w) * DHH * NN;
  short8v qf[2];
#pragma unroll
  for (int kc = 0; kc < 2; ++kc)
    qf[kc] = *(const short8v*)&qb[l16 * DHH + kc * 32 + lg * 8];
  f32x4 acc[4];
  const f32x4 z = {0.f, 0.f, 0.f, 0.f};
#pragma unroll
  for (int d = 0; d < 4; ++d) acc[d] = z;
  float mrow[4], lrow[4];
#pragma unroll
  for (int r = 0; r < 4; ++r) { mrow[r] = -1e30f; lrow[r] = 0.f; }
  _Float16* hb = (_Float16*)&wavebuf[w][0];
  unsigned char* ps = &wavebuf[w][0];
  __syncthreads();
  const float4 vi_a = sv4[i0 + w * 2], vi_b = sv4[i0 + w * 2 + 1];
  const int ti_a = stt[i0 + w * 2], ti_b = stt[i0 + w * 2 + 1];
  for (int j0 = 0; j0 < NN; j0 += 64) {
    // ---- Phase A: bias MLP for (16 i) x (64 j), all heads, cooperative ----
#pragma unroll
    for (int tt = 0; tt < 8; ++tt) {
      const int jg = tt & 3;
      const int sec = tt >> 2;
      const float4 vi = sec ? vi_b : vi_a;
      const int ti = sec ? ti_b : ti_a;
      const int il = w * 2 + sec;
      const int j = j0 + jg * 16 + l16;
      const float4 vj = sv4[j];
      f16x8 af = {0, 0, 0, 0, 0, 0, 0, 0};
      if (lg == 0) {
        af[0] = (_Float16)(vi.x - vj.x); af[1] = (_Float16)(vi.y - vj.y);
        af[2] = (_Float16)(vi.z - vj.z); af[3] = (_Float16)(vi.w - vj.w);
        af[4] = (_Float16)(vi.x * vj.x); af[5] = (_Float16)(vi.y * vj.y);
        af[6] = (_Float16)(vi.z * vj.z); af[7] = (_Float16)(vi.w * vj.w);
      } else if (lg == 1) {
        af[0] = (ti == stt[j]) ? (_Float16)1.f : (_Float16)0.f;
      }
      f32x4 h0 = {b1v0, b1v0, b1v0, b1v0};
      f32x4 h1 = {b1v1, b1v1, b1v1, b1v1};
      h0 = __builtin_amdgcn_mfma_f32_16x16x32_f16(af, w1f[0], h0, 0, 0, 0);
      h1 = __builtin_amdgcn_mfma_f32_16x16x32_f16(af, w1f[1], h1, 0, 0, 0);
      // relu + transpose through per-wave LDS (row stride 40 halfs = 80B)
#pragma unroll
      for (int r = 0; r < 4; ++r) {
        const int row = lg * 4 + r;
        hb[row * 40 + l16] = (_Float16)fmaxf(h0[r], 0.f);
        hb[row * 40 + 16 + l16] = (_Float16)fmaxf(h1[r], 0.f);
      }
      f16x8 af2 = *(const f16x8*)&hb[l16 * 40 + lg * 8];
      f32x4 o = {b2v, b2v, b2v, b2v};
      o = __builtin_amdgcn_mfma_f32_16x16x32_f16(af2, w2f, o, 0, 0, 0);
      // store: head = l16 (<8), pair = lg*4+r -> bias_lds[il][(jrel*8+h)^K2]
      if (l16 < 8) {
        const int K2 = (il >> 2) << 1;
        const int base = il * 512;
#pragma unroll
        for (int r = 0; r < 4; ++r) {
          const int jrel = jg * 16 + lg * 4 + r;
          bias_lds[base + ((jrel * 8 + l16) ^ K2)] =
              __builtin_bit_cast(unsigned short, (_Float16)o[r]);
        }
      }
    }
    __syncthreads();  // bias tile ready
    // ---- Phase B: QK^T + bias + mask ----
    f32x4 s[4];
#pragma unroll
    for (int jt = 0; jt < 4; ++jt) {
      const unsigned short* kr = &kb[(j0 + jt * 16 + l16) * DHH + lg * 8];
      short8v kf0 = *(const short8v*)&kr[0];
      short8v kf1 = *(const short8v*)&kr[32];
      f32x4 t = z;
      t = __builtin_amdgcn_mfma_f32_16x16x32_bf16(qf[0], kf0, t, 0, 0, 0);
      t = __builtin_amdgcn_mfma_f32_16x16x32_bf16(qf[1], kf1, t, 0, 0, 0);
      s[jt] = t;
    }
    const int K2b = lg << 1;  // ((i>>2)&3)<<1 with i = lg*4+r
#pragma unroll
    for (int jt = 0; jt < 4; ++jt) {
      const int jrel = jt * 16 + l16;
      const float mk = smask[j0 + jrel];
#pragma unroll
      for (int r = 0; r < 4; ++r) {
        const unsigned short raw = bias_lds[(lg * 4 + r) * 512 + ((jrel * 8 + w) ^ K2b)];
        const float bv = (float)__builtin_bit_cast(_Float16, raw);
        s[jt][r] = fmaf(s[jt][r], 0.125f, bv) + mk;
      }
    }
    __syncthreads();  // all bias reads done -> next Phase A may overwrite bias_lds/wavebuf
    // ---- online softmax ----
    float alpha[4];
#pragma unroll
    for (int r = 0; r < 4; ++r) {
      float tm = fmaxf(fmaxf(s[0][r], s[1][r]), fmaxf(s[2][r], s[3][r]));
      tm = fmaxf(tm, __shfl_xor(tm, 1));
      tm = fmaxf(tm, __shfl_xor(tm, 2));
      tm = fmaxf(tm, __shfl_xor(tm, 4));
      tm = fmaxf(tm, __shfl_xor(tm, 8));
      const float mn = fmaxf(mrow[r], tm);
      alpha[r] = __expf(mrow[r] - mn);
      mrow[r] = mn;
      float ts = 0.f;
#pragma unroll
      for (int jt = 0; jt < 4; ++jt) {
        const float p = __expf(s[jt][r] - mn);
        s[jt][r] = p;
        ts += p;
      }
      ts += __shfl_xor(ts, 1);
      ts += __shfl_xor(ts, 2);
      ts += __shfl_xor(ts, 4);
      ts += __shfl_xor(ts, 8);
      lrow[r] = lrow[r] * alpha[r] + ts;
    }
#pragma unroll
    for (int d = 0; d < 4; ++d)
#pragma unroll
      for (int r = 0; r < 4; ++r) acc[d][r] *= alpha[r];
    // P -> bf16 -> per-wave LDS (swz128, conflict-free; wave-local so no barrier needed)
#pragma unroll
    for (int jt = 0; jt < 4; ++jt)
#pragma unroll
      for (int r = 0; r < 4; ++r)
        *(unsigned short*)&ps[swz128(lg * 4 + r, jt * 32 + 2 * l16)] = f2bf(s[jt][r]);
    short8v pf[2];
#pragma unroll
    for (int kc = 0; kc < 2; ++kc)
      pf[kc] = *(const short8v*)&ps[swz128(l16, kc * 64 + lg * 16)];
    // PV: B-frags straight from global V^T (L2-resident)
#pragma unroll
    for (int d = 0; d < 4; ++d) {
      const unsigned short* vr = &vtb[(size_t)(d * 16 + l16) * NN + j0 + lg * 8];
      short8v vf0 = *(const short8v*)&vr[0];
      short8v vf1 = *(const short8v*)&vr[32];
      acc[d] = __builtin_amdgcn_mfma_f32_16x16x32_bf16(pf[0], vf0, acc[d], 0, 0, 0);
      acc[d] = __builtin_amdgcn_mfma_f32_16x16x32_bf16(pf[1], vf1, acc[d], 0, 0, 0);
    }
  }
  // epilogue: normalize, store attn_out bf16 [b][n][h*64+dh]
#pragma unroll
  for (int d = 0; d < 4; ++d) {
#pragma unroll
    for (int r = 0; r < 4; ++r) {
      const int row = i0 + lg * 4 + r;
      ao[(size_t)(b_ * NN + row) * 512 + w * DHH + d * 16 + l16] =
          f2bf(acc[d][r] / lrow[r]);
    }
  }
}

extern "C" void kernel_launch(void* const* d_in, const int* in_sizes, int n_in,
                              void* d_out, int out_size, void* d_ws, size_t ws_size,
                              hipStream_t stream) {
  const float* h     = (const float*)d_in[0];
  const float* v     = (const float*)d_in[1];
  const int*   m     = (const int*)d_in[2];
  const int*   tti   = (const int*)d_in[3];
  const float* W_qkv = (const float*)d_in[4];
  const float* W_out = (const float*)d_in[5];
  const float* W1    = (const float*)d_in[6];
  const float* b1    = (const float*)d_in[7];
  const float* W2    = (const float*)d_in[8];
  const float* b2    = (const float*)d_in[9];
  float* out = (float*)d_out;
  unsigned char* ws = (unsigned char*)d_ws;

  unsigned short* h_bf  = (unsigned short*)(ws + 0);
  unsigned short* q_bf  = (unsigned short*)(ws + 8388608);
  unsigned short* k_bf  = (unsigned short*)(ws + 16777216);
  unsigned short* vt_bf = (unsigned short*)(ws + 25165824);
  unsigned short* ao_bf = (unsigned short*)(ws + 33554432);
  unsigned short* WqT   = (unsigned short*)(ws + 41943040);
  unsigned short* WoT   = (unsigned short*)(ws + 43515904);

  cvt_bf<<<4096, 256, 0, stream>>>(h, h_bf, 16 * NN * 512);
  transpose_cvt<<<dim3(16, 48), 256, 0, stream>>>(W_qkv, WqT, 512, 1536);
  transpose_cvt<<<dim3(16, 16), 256, 0, stream>>>(W_out, WoT, 512, 512);
  gemm_qkv<<<dim3(64, 12), 256, 0, stream>>>(h_bf, WqT, q_bf, k_bf, vt_bf);
  attn_bias_fused<<<dim3(32, 16), 512, 0, stream>>>(q_bf, k_bf, vt_bf, v, tti, m,
                                                    W1, b1, W2, b2, ao_bf);
  gemm_out<<<dim3(64, 4), 256, 0, stream>>>(ao_bf, WoT, m, out);
}

// Round 7
// 231.831 us; speedup vs baseline: 1.0061x; 1.0061x over previous
//
#include <hip/hip_runtime.h>
#include <hip/hip_bf16.h>
#include <hip/hip_fp16.h>

// B=16, N=512, D=512, H=8, DH=64, PD=9, HID=32
#define NN 512
#define HH 8
#define DHH 64

typedef __attribute__((ext_vector_type(8))) short short8v;
typedef __attribute__((ext_vector_type(8))) unsigned short ushort8v;
typedef __attribute__((ext_vector_type(4))) unsigned short ushort4v;
typedef __attribute__((ext_vector_type(4))) float f32x4;
typedef __attribute__((ext_vector_type(8))) _Float16 f16x8;

__device__ __forceinline__ unsigned short f2bf(float x) {
  unsigned u = __builtin_bit_cast(unsigned, x);
  u += 0x7FFFu + ((u >> 16) & 1u);
  return (unsigned short)(u >> 16);
}
__device__ __forceinline__ int swz64(int r, int cb) { return r * 64 + (cb ^ (((r >> 1) & 3) << 4)); }
__device__ __forceinline__ int swz128(int r, int cb) { return r * 128 + (cb ^ ((r & 7) << 4)); }

// ---------------- fp32 -> bf16 elementwise ----------------
__global__ __launch_bounds__(256) void cvt_bf(const float* __restrict__ src,
                                              unsigned short* __restrict__ dst, int n) {
  int i = (blockIdx.x * 256 + threadIdx.x) * 4;
  if (i < n) {
    float4 v = *(const float4*)&src[i];
    ushort4v o;
    o[0] = f2bf(v.x); o[1] = f2bf(v.y); o[2] = f2bf(v.z); o[3] = f2bf(v.w);
    *(ushort4v*)&dst[i] = o;
  }
}

// ---------------- transpose + cvt: src fp32 [R][C] -> dst bf16 [C][R] ----------------
__global__ __launch_bounds__(256) void transpose_cvt(const float* __restrict__ src,
                                                     unsigned short* __restrict__ dst,
                                                     int R, int C) {
  __shared__ float t[32][33];
  const int r0 = blockIdx.x * 32, c0 = blockIdx.y * 32;
  const int rr = threadIdx.x >> 3, c4 = (threadIdx.x & 7) * 4;
  float4 v = *(const float4*)&src[(size_t)(r0 + rr) * C + c0 + c4];
  t[rr][c4 + 0] = v.x; t[rr][c4 + 1] = v.y; t[rr][c4 + 2] = v.z; t[rr][c4 + 3] = v.w;
  __syncthreads();
  ushort4v o;
#pragma unroll
  for (int e = 0; e < 4; ++e) o[e] = f2bf(t[c4 + e][rr]);
  *(ushort4v*)&dst[(size_t)(c0 + rr) * R + r0 + c4] = o;
}

// ---------------- shared 128x128 bf16 MFMA GEMM body (BK=32, 4 waves) ----------------
__device__ __forceinline__ void gemm128_body(const unsigned short* __restrict__ A,
                                             const unsigned short* __restrict__ Bt,
                                             int ldk, int m0, int n0,
                                             f32x4 acc[4][4], unsigned char* smem) {
  const int tid = threadIdx.x, lane = tid & 63, wid = tid >> 6;
  const int wm = wid >> 1, wn = wid & 1;
  int aoff[4], boff[4];
#pragma unroll
  for (int i = 0; i < 4; ++i) {
    aoff[i] = swz64(wm * 64 + i * 16 + (lane & 15), (lane >> 4) * 16);
    boff[i] = 8192 + swz64(wn * 64 + i * 16 + (lane & 15), (lane >> 4) * 16);
  }
  for (int k0 = 0; k0 < ldk; k0 += 32) {
#pragma unroll
    for (int p = 0; p < 2; ++p) {
      const int idx = p * 256 + tid;
      const int r = idx >> 2, cg = idx & 3;
      ushort8v av = *(const ushort8v*)&A[(size_t)(m0 + r) * ldk + k0 + cg * 8];
      *(ushort8v*)&smem[swz64(r, cg * 16)] = av;
      ushort8v bv = *(const ushort8v*)&Bt[(size_t)(n0 + r) * ldk + k0 + cg * 8];
      *(ushort8v*)&smem[8192 + swz64(r, cg * 16)] = bv;
    }
    __syncthreads();
    short8v a[4], b[4];
#pragma unroll
    for (int i = 0; i < 4; ++i) {
      a[i] = *(const short8v*)&smem[aoff[i]];
      b[i] = *(const short8v*)&smem[boff[i]];
    }
#pragma unroll
    for (int i = 0; i < 4; ++i)
#pragma unroll
      for (int j = 0; j < 4; ++j)
        acc[i][j] = __builtin_amdgcn_mfma_f32_16x16x32_bf16(a[i], b[j], acc[i][j], 0, 0, 0);
    __syncthreads();
  }
}

// ---------------- QKV GEMM -> q [bh][n][dh], k [bh][n][dh], v TRANSPOSED [bh][dh][n] ----------------
__global__ __launch_bounds__(256) void gemm_qkv(const unsigned short* __restrict__ A,
                                                const unsigned short* __restrict__ Bt,
                                                unsigned short* __restrict__ q,
                                                unsigned short* __restrict__ k,
                                                unsigned short* __restrict__ vt) {
  __shared__ unsigned char smem[16384];
  f32x4 acc[4][4];
  const f32x4 z = {0.f, 0.f, 0.f, 0.f};
#pragma unroll
  for (int i = 0; i < 4; ++i)
#pragma unroll
    for (int j = 0; j < 4; ++j) acc[i][j] = z;
  gemm128_body(A, Bt, 512, blockIdx.x * 128, blockIdx.y * 128, acc, smem);
  const int lane = threadIdx.x & 63, wid = threadIdx.x >> 6;
  const int wm = wid >> 1, wn = wid & 1;
#pragma unroll
  for (int i = 0; i < 4; ++i) {
    const int row0 = blockIdx.x * 128 + wm * 64 + i * 16 + ((lane >> 4) << 2);
#pragma unroll
    for (int j = 0; j < 4; ++j) {
      const int col = blockIdx.y * 128 + wn * 64 + j * 16 + (lane & 15);
      const int part = col >> 9, head = (col >> 6) & 7, dh = col & 63;
      if (part == 2) {
        // V^T: 4 consecutive n -> one 8B store
        const int b_ = row0 >> 9, n_ = row0 & 511;
        ushort4v pk;
#pragma unroll
        for (int rr = 0; rr < 4; ++rr) pk[rr] = f2bf(acc[i][j][rr]);
        *(ushort4v*)&vt[(((b_ * HH + head) * DHH) + dh) * NN + n_] = pk;
      } else {
        unsigned short* dst = (part == 0) ? q : k;
#pragma unroll
        for (int rr = 0; rr < 4; ++rr) {
          const int row = row0 + rr;
          const int b_ = row >> 9, n_ = row & 511;
          dst[(((b_ * HH + head) * NN) + n_) * DHH + dh] = f2bf(acc[i][j][rr]);
        }
      }
    }
  }
}

// ---------------- out GEMM: ao_bf[8192][512] @ WoT[512][512]^T -> fp32 out (masked) ----------------
__global__ __launch_bounds__(256) void gemm_out(const unsigned short* __restrict__ A,
                                                const unsigned short* __restrict__ Bt,
                                                const int* __restrict__ msk,
                                                float* __restrict__ out) {
  __shared__ unsigned char smem[16384];
  f32x4 acc[4][4];
  const f32x4 z = {0.f, 0.f, 0.f, 0.f};
#pragma unroll
  for (int i = 0; i < 4; ++i)
#pragma unroll
    for (int j = 0; j < 4; ++j) acc[i][j] = z;
  gemm128_body(A, Bt, 512, blockIdx.x * 128, blockIdx.y * 128, acc, smem);
  const int lane = threadIdx.x & 63, wid = threadIdx.x >> 6;
  const int wm = wid >> 1, wn = wid & 1;
#pragma unroll
  for (int i = 0; i < 4; ++i) {
    const int row0 = blockIdx.x * 128 + wm * 64 + i * 16 + ((lane >> 4) << 2);
#pragma unroll
    for (int j = 0; j < 4; ++j) {
      const int col = blockIdx.y * 128 + wn * 64 + j * 16 + (lane & 15);
#pragma unroll
      for (int rr = 0; rr < 4; ++rr) {
        const int row = row0 + rr;
        const float mm = (msk[row] != 0) ? 1.f : 0.f;
        out[(size_t)row * 512 + col] = acc[i][j][rr] * mm;
      }
    }
  }
}

// ---------------- FUSED pairwise-bias MLP + flash attention (v4) ----------------
// = round-4 structure EXACTLY (double-buffered bias, ONE barrier per j-tile,
//   separate hbuf/ps, ~72KB LDS, 2 blocks/CU) with a single change:
//   bias LDS layout -> [buf][i][ (j*8+h) ^ ((i>>2)<<1) ]  (writer <=4-way,
//   reader 2-way=free; round-4 layout was 8-way on writes).
__global__ __launch_bounds__(512, 4) void attn_bias_fused(
    const unsigned short* __restrict__ q, const unsigned short* __restrict__ k,
    const unsigned short* __restrict__ vt, const float* __restrict__ vvec,
    const int* __restrict__ tti, const int* __restrict__ msk,
    const float* __restrict__ W1, const float* __restrict__ b1,
    const float* __restrict__ W2, const float* __restrict__ b2,
    unsigned short* __restrict__ ao) {
  __shared__ float4 sv4[NN];
  __shared__ int stt[NN];
  __shared__ float smask[NN];
  __shared__ unsigned short bias_lds[2][16 * 512];  // 32KB double-buffered, XOR layout
  __shared__ _Float16 hbuf[HH][16 * 40];            // per-wave MLP transpose (round-4)
  __shared__ unsigned char ps[HH][2048];            // per-wave P tile (swz128)
  const int tid = threadIdx.x, lane = tid & 63, w = tid >> 6;
  const int l16 = lane & 15, lg = lane >> 4;
  const int it = blockIdx.x, b_ = blockIdx.y;
  const int i0 = it * 16;
  for (int idx = tid; idx < NN; idx += 512) {
    sv4[idx] = *(const float4*)&vvec[(b_ * NN + idx) * 4];
    stt[idx] = tti[idx];
    smask[idx] = (msk[b_ * NN + idx] != 0) ? 0.f : -1e30f;
  }
  // MLP weight fragments (round-4 proven): W1 B-frag (col=c), W2 B-frag (col=head)
  f16x8 w1f[2], w2f;
#pragma unroll
  for (int t = 0; t < 2; ++t)
#pragma unroll
    for (int e = 0; e < 8; ++e) {
      const int kk = lg * 8 + e;
      w1f[t][e] = (kk < 9) ? (_Float16)W1[kk * 32 + t * 16 + l16] : (_Float16)0.f;
    }
#pragma unroll
  for (int e = 0; e < 8; ++e)
    w2f[e] = (l16 < 8) ? (_Float16)W2[(lg * 8 + e) * 8 + l16] : (_Float16)0.f;
  const float b1v0 = b1[l16], b1v1 = b1[16 + l16];
  const float b2v = (l16 < 8) ? b2[l16] : 0.f;
  // per-head attention state
  const unsigned short* qb = q + ((size_t)(b_ * HH + w) * NN + i0) * DHH;
  const unsigned short* kb = k + (size_t)(b_ * HH + w) * NN * DHH;
  const unsigned short* vtb = vt + (size_t)(b_ * HH + w) * DHH * NN;
  short8v qf[2];
#pragma unroll
  for (int kc = 0; kc < 2; ++kc)
    qf[kc] = *(const short8v*)&qb[l16 * DHH + kc * 32 + lg * 8];
  f32x4 acc[4];
  const f32x4 z = {0.f, 0.f, 0.f, 0.f};
#pragma unroll
  for (int d = 0; d < 4; ++d) acc[d] = z;
  float mrow[4], lrow[4];
#pragma unroll
  for (int r = 0; r < 4; ++r) { mrow[r] = -1e30f; lrow[r] = 0.f; }
  _Float16* hb = &hbuf[w][0];
  unsigned char* psw = &ps[w][0];
  __syncthreads();
  const float4 vi_a = sv4[i0 + w * 2], vi_b = sv4[i0 + w * 2 + 1];
  const int ti_a = stt[i0 + w * 2], ti_b = stt[i0 + w * 2 + 1];
  int pbuf = 0;
  for (int j0 = 0; j0 < NN; j0 += 64) {
    // ---- Phase A: bias MLP for (16 i) x (64 j), all heads, cooperative ----
#pragma unroll
    for (int tt = 0; tt < 8; ++tt) {
      const int jg = tt & 3;
      const int sec = tt >> 2;
      const float4 vi = sec ? vi_b : vi_a;
      const int ti = sec ? ti_b : ti_a;
      const int il = w * 2 + sec;
      const int j = j0 + jg * 16 + l16;
      const float4 vj = sv4[j];
      f16x8 af = {0, 0, 0, 0, 0, 0, 0, 0};
      if (lg == 0) {
        af[0] = (_Float16)(vi.x - vj.x); af[1] = (_Float16)(vi.y - vj.y);
        af[2] = (_Float16)(vi.z - vj.z); af[3] = (_Float16)(vi.w - vj.w);
        af[4] = (_Float16)(vi.x * vj.x); af[5] = (_Float16)(vi.y * vj.y);
        af[6] = (_Float16)(vi.z * vj.z); af[7] = (_Float16)(vi.w * vj.w);
      } else if (lg == 1) {
        af[0] = (ti == stt[j]) ? (_Float16)1.f : (_Float16)0.f;
      }
      f32x4 h0 = {b1v0, b1v0, b1v0, b1v0};
      f32x4 h1 = {b1v1, b1v1, b1v1, b1v1};
      h0 = __builtin_amdgcn_mfma_f32_16x16x32_f16(af, w1f[0], h0, 0, 0, 0);
      h1 = __builtin_amdgcn_mfma_f32_16x16x32_f16(af, w1f[1], h1, 0, 0, 0);
      // relu + transpose through per-wave LDS (row stride 40 halfs = 80B)
#pragma unroll
      for (int r = 0; r < 4; ++r) {
        const int row = lg * 4 + r;
        hb[row * 40 + l16] = (_Float16)fmaxf(h0[r], 0.f);
        hb[row * 40 + 16 + l16] = (_Float16)fmaxf(h1[r], 0.f);
      }
      f16x8 af2 = *(const f16x8*)&hb[l16 * 40 + lg * 8];
      f32x4 o = {b2v, b2v, b2v, b2v};
      o = __builtin_amdgcn_mfma_f32_16x16x32_f16(af2, w2f, o, 0, 0, 0);
      // store: head = l16 (<8), pair = jg*16 + lg*4 + r -> bias_lds[pbuf][il][(jrel*8+h)^K2]
      if (l16 < 8) {
        const int K2 = (il >> 2) << 1;
        const int base = il * 512;
#pragma unroll
        for (int r = 0; r < 4; ++r) {
          const int jrel = jg * 16 + lg * 4 + r;
          bias_lds[pbuf][base + ((jrel * 8 + l16) ^ K2)] =
              __builtin_bit_cast(unsigned short, (_Float16)o[r]);
        }
      }
    }
    __syncthreads();  // bias tile ready (prev tile's reads protected by dbuf)
    // ---- Phase B: QK^T + bias + mask ----
    f32x4 s[4];
#pragma unroll
    for (int jt = 0; jt < 4; ++jt) {
      const unsigned short* kr = &kb[(j0 + jt * 16 + l16) * DHH + lg * 8];
      short8v kf0 = *(const short8v*)&kr[0];
      short8v kf1 = *(const short8v*)&kr[32];
      f32x4 t = z;
      t = __builtin_amdgcn_mfma_f32_16x16x32_bf16(qf[0], kf0, t, 0, 0, 0);
      t = __builtin_amdgcn_mfma_f32_16x16x32_bf16(qf[1], kf1, t, 0, 0, 0);
      s[jt] = t;
    }
    const int K2b = lg << 1;  // ((i>>2))<<1 with i = lg*4+r
#pragma unroll
    for (int jt = 0; jt < 4; ++jt) {
      const int jrel = jt * 16 + l16;
      const float mk = smask[j0 + jrel];
#pragma unroll
      for (int r = 0; r < 4; ++r) {
        const unsigned short raw =
            bias_lds[pbuf][(lg * 4 + r) * 512 + ((jrel * 8 + w) ^ K2b)];
        const float bv = (float)__builtin_bit_cast(_Float16, raw);
        s[jt][r] = fmaf(s[jt][r], 0.125f, bv) + mk;
      }
    }
    // ---- online softmax ----
    float alpha[4];
#pragma unroll
    for (int r = 0; r < 4; ++r) {
      float tm = fmaxf(fmaxf(s[0][r], s[1][r]), fmaxf(s[2][r], s[3][r]));
      tm = fmaxf(tm, __shfl_xor(tm, 1));
      tm = fmaxf(tm, __shfl_xor(tm, 2));
      tm = fmaxf(tm, __shfl_xor(tm, 4));
      tm = fmaxf(tm, __shfl_xor(tm, 8));
      const float mn = fmaxf(mrow[r], tm);
      alpha[r] = __expf(mrow[r] - mn);
      mrow[r] = mn;
      float ts = 0.f;
#pragma unroll
      for (int jt = 0; jt < 4; ++jt) {
        const float p = __expf(s[jt][r] - mn);
        s[jt][r] = p;
        ts += p;
      }
      ts += __shfl_xor(ts, 1);
      ts += __shfl_xor(ts, 2);
      ts += __shfl_xor(ts, 4);
      ts += __shfl_xor(ts, 8);
      lrow[r] = lrow[r] * alpha[r] + ts;
    }
#pragma unroll
    for (int d = 0; d < 4; ++d)
#pragma unroll
      for (int r = 0; r < 4; ++r) acc[d][r] *= alpha[r];
    // P -> bf16 -> per-wave LDS (swz128, conflict-free; wave-local, no barrier)
#pragma unroll
    for (int jt = 0; jt < 4; ++jt)
#pragma unroll
      for (int r = 0; r < 4; ++r)
        *(unsigned short*)&psw[swz128(lg * 4 + r, jt * 32 + 2 * l16)] = f2bf(s[jt][r]);
    short8v pf[2];
#pragma unroll
    for (int kc = 0; kc < 2; ++kc)
      pf[kc] = *(const short8v*)&psw[swz128(l16, kc * 64 + lg * 16)];
    // PV: B-frags straight from global V^T (L2-resident)
#pragma unroll
    for (int d = 0; d < 4; ++d) {
      const unsigned short* vr = &vtb[(size_t)(d * 16 + l16) * NN + j0 + lg * 8];
      short8v vf0 = *(const short8v*)&vr[0];
      short8v vf1 = *(const short8v*)&vr[32];
      acc[d] = __builtin_amdgcn_mfma_f32_16x16x32_bf16(pf[0], vf0, acc[d], 0, 0, 0);
      acc[d] = __builtin_amdgcn_mfma_f32_16x16x32_bf16(pf[1], vf1, acc[d], 0, 0, 0);
    }
    pbuf ^= 1;
  }
  // epilogue: normalize, store attn_out bf16 [b][n][h*64+dh]
#pragma unroll
  for (int d = 0; d < 4; ++d) {
#pragma unroll
    for (int r = 0; r < 4; ++r) {
      const int row = i0 + lg * 4 + r;
      ao[(size_t)(b_ * NN + row) * 512 + w * DHH + d * 16 + l16] =
          f2bf(acc[d][r] / lrow[r]);
    }
  }
}

extern "C" void kernel_launch(void* const* d_in, const int* in_sizes, int n_in,
                              void* d_out, int out_size, void* d_ws, size_t ws_size,
                              hipStream_t stream) {
  const float* h     = (const float*)d_in[0];
  const float* v     = (const float*)d_in[1];
  const int*   m     = (const int*)d_in[2];
  const int*   tti   = (const int*)d_in[3];
  const float* W_qkv = (const float*)d_in[4];
  const float* W_out = (const float*)d_in[5];
  const float* W1    = (const float*)d_in[6];
  const float* b1    = (const float*)d_in[7];
  const float* W2    = (const float*)d_in[8];
  const float* b2    = (const float*)d_in[9];
  float* out = (float*)d_out;
  unsigned char* ws = (unsigned char*)d_ws;

  unsigned short* h_bf  = (unsigned short*)(ws + 0);
  unsigned short* q_bf  = (unsigned short*)(ws + 8388608);
  unsigned short* k_bf  = (unsigned short*)(ws + 16777216);
  unsigned short* vt_bf = (unsigned short*)(ws + 25165824);
  unsigned short* ao_bf = (unsigned short*)(ws + 33554432);
  unsigned short* WqT   = (unsigned short*)(ws + 41943040);
  unsigned short* WoT   = (unsigned short*)(ws + 43515904);

  cvt_bf<<<4096, 256, 0, stream>>>(h, h_bf, 16 * NN * 512);
  transpose_cvt<<<dim3(16, 48), 256, 0, stream>>>(W_qkv, WqT, 512, 1536);
  transpose_cvt<<<dim3(16, 16), 256, 0, stream>>>(W_out, WoT, 512, 512);
  gemm_qkv<<<dim3(64, 12), 256, 0, stream>>>(h_bf, WqT, q_bf, k_bf, vt_bf);
  attn_bias_fused<<<dim3(32, 16), 512, 0, stream>>>(q_bf, k_bf, vt_bf, v, tti, m,
                                                    W1, b1, W2, b2, ao_bf);
  gemm_out<<<dim3(64, 4), 256, 0, stream>>>(ao_bf, WoT, m, out);
}

// Round 8
// 211.965 us; speedup vs baseline: 1.1004x; 1.0937x over previous
//
#include <hip/hip_runtime.h>
#include <hip/hip_bf16.h>
#include <hip/hip_fp16.h>

// B=16, N=512, D=512, H=8, DH=64, PD=9, HID=32
#define NN 512
#define HH 8
#define DHH 64

typedef __attribute__((ext_vector_type(8))) short short8v;
typedef __attribute__((ext_vector_type(8))) unsigned short ushort8v;
typedef __attribute__((ext_vector_type(4))) unsigned short ushort4v;
typedef __attribute__((ext_vector_type(4))) float f32x4;
typedef __attribute__((ext_vector_type(8))) _Float16 f16x8;
typedef __attribute__((ext_vector_type(4))) _Float16 f16x4;

__device__ __forceinline__ unsigned short f2bf(float x) {
  unsigned u = __builtin_bit_cast(unsigned, x);
  u += 0x7FFFu + ((u >> 16) & 1u);
  return (unsigned short)(u >> 16);
}
__device__ __forceinline__ int swz64(int r, int cb) { return r * 64 + (cb ^ (((r >> 1) & 3) << 4)); }
__device__ __forceinline__ int swz128(int r, int cb) { return r * 128 + (cb ^ ((r & 7) << 4)); }

// ---------------- fp32 -> bf16 elementwise ----------------
__global__ __launch_bounds__(256) void cvt_bf(const float* __restrict__ src,
                                              unsigned short* __restrict__ dst, int n) {
  int i = (blockIdx.x * 256 + threadIdx.x) * 4;
  if (i < n) {
    float4 v = *(const float4*)&src[i];
    ushort4v o;
    o[0] = f2bf(v.x); o[1] = f2bf(v.y); o[2] = f2bf(v.z); o[3] = f2bf(v.w);
    *(ushort4v*)&dst[i] = o;
  }
}

// ---------------- transpose + cvt: src fp32 [R][C] -> dst bf16 [C][R] ----------------
__global__ __launch_bounds__(256) void transpose_cvt(const float* __restrict__ src,
                                                     unsigned short* __restrict__ dst,
                                                     int R, int C) {
  __shared__ float t[32][33];
  const int r0 = blockIdx.x * 32, c0 = blockIdx.y * 32;
  const int rr = threadIdx.x >> 3, c4 = (threadIdx.x & 7) * 4;
  float4 v = *(const float4*)&src[(size_t)(r0 + rr) * C + c0 + c4];
  t[rr][c4 + 0] = v.x; t[rr][c4 + 1] = v.y; t[rr][c4 + 2] = v.z; t[rr][c4 + 3] = v.w;
  __syncthreads();
  ushort4v o;
#pragma unroll
  for (int e = 0; e < 4; ++e) o[e] = f2bf(t[c4 + e][rr]);
  *(ushort4v*)&dst[(size_t)(c0 + rr) * R + r0 + c4] = o;
}

// ---------------- shared 128x128 bf16 MFMA GEMM body (BK=32, 4 waves) ----------------
__device__ __forceinline__ void gemm128_body(const unsigned short* __restrict__ A,
                                             const unsigned short* __restrict__ Bt,
                                             int ldk, int m0, int n0,
                                             f32x4 acc[4][4], unsigned char* smem) {
  const int tid = threadIdx.x, lane = tid & 63, wid = tid >> 6;
  const int wm = wid >> 1, wn = wid & 1;
  int aoff[4], boff[4];
#pragma unroll
  for (int i = 0; i < 4; ++i) {
    aoff[i] = swz64(wm * 64 + i * 16 + (lane & 15), (lane >> 4) * 16);
    boff[i] = 8192 + swz64(wn * 64 + i * 16 + (lane & 15), (lane >> 4) * 16);
  }
  for (int k0 = 0; k0 < ldk; k0 += 32) {
#pragma unroll
    for (int p = 0; p < 2; ++p) {
      const int idx = p * 256 + tid;
      const int r = idx >> 2, cg = idx & 3;
      ushort8v av = *(const ushort8v*)&A[(size_t)(m0 + r) * ldk + k0 + cg * 8];
      *(ushort8v*)&smem[swz64(r, cg * 16)] = av;
      ushort8v bv = *(const ushort8v*)&Bt[(size_t)(n0 + r) * ldk + k0 + cg * 8];
      *(ushort8v*)&smem[8192 + swz64(r, cg * 16)] = bv;
    }
    __syncthreads();
    short8v a[4], b[4];
#pragma unroll
    for (int i = 0; i < 4; ++i) {
      a[i] = *(const short8v*)&smem[aoff[i]];
      b[i] = *(const short8v*)&smem[boff[i]];
    }
#pragma unroll
    for (int i = 0; i < 4; ++i)
#pragma unroll
      for (int j = 0; j < 4; ++j)
        acc[i][j] = __builtin_amdgcn_mfma_f32_16x16x32_bf16(a[i], b[j], acc[i][j], 0, 0, 0);
    __syncthreads();
  }
}

// ---------------- QKV GEMM -> q [bh][n][dh], k [bh][n][dh], v TRANSPOSED [bh][dh][n] ----------------
__global__ __launch_bounds__(256) void gemm_qkv(const unsigned short* __restrict__ A,
                                                const unsigned short* __restrict__ Bt,
                                                unsigned short* __restrict__ q,
                                                unsigned short* __restrict__ k,
                                                unsigned short* __restrict__ vt) {
  __shared__ unsigned char smem[16384];
  f32x4 acc[4][4];
  const f32x4 z = {0.f, 0.f, 0.f, 0.f};
#pragma unroll
  for (int i = 0; i < 4; ++i)
#pragma unroll
    for (int j = 0; j < 4; ++j) acc[i][j] = z;
  gemm128_body(A, Bt, 512, blockIdx.x * 128, blockIdx.y * 128, acc, smem);
  const int lane = threadIdx.x & 63, wid = threadIdx.x >> 6;
  const int wm = wid >> 1, wn = wid & 1;
#pragma unroll
  for (int i = 0; i < 4; ++i) {
    const int row0 = blockIdx.x * 128 + wm * 64 + i * 16 + ((lane >> 4) << 2);
#pragma unroll
    for (int j = 0; j < 4; ++j) {
      const int col = blockIdx.y * 128 + wn * 64 + j * 16 + (lane & 15);
      const int part = col >> 9, head = (col >> 6) & 7, dh = col & 63;
      if (part == 2) {
        // V^T: 4 consecutive n -> one 8B store
        const int b_ = row0 >> 9, n_ = row0 & 511;
        ushort4v pk;
#pragma unroll
        for (int rr = 0; rr < 4; ++rr) pk[rr] = f2bf(acc[i][j][rr]);
        *(ushort4v*)&vt[(((b_ * HH + head) * DHH) + dh) * NN + n_] = pk;
      } else {
        unsigned short* dst = (part == 0) ? q : k;
#pragma unroll
        for (int rr = 0; rr < 4; ++rr) {
          const int row = row0 + rr;
          const int b_ = row >> 9, n_ = row & 511;
          dst[(((b_ * HH + head) * NN) + n_) * DHH + dh] = f2bf(acc[i][j][rr]);
        }
      }
    }
  }
}

// ---------------- out GEMM: ao_bf[8192][512] @ WoT[512][512]^T -> fp32 out (masked) ----------------
__global__ __launch_bounds__(256) void gemm_out(const unsigned short* __restrict__ A,
                                                const unsigned short* __restrict__ Bt,
                                                const int* __restrict__ msk,
                                                float* __restrict__ out) {
  __shared__ unsigned char smem[16384];
  f32x4 acc[4][4];
  const f32x4 z = {0.f, 0.f, 0.f, 0.f};
#pragma unroll
  for (int i = 0; i < 4; ++i)
#pragma unroll
    for (int j = 0; j < 4; ++j) acc[i][j] = z;
  gemm128_body(A, Bt, 512, blockIdx.x * 128, blockIdx.y * 128, acc, smem);
  const int lane = threadIdx.x & 63, wid = threadIdx.x >> 6;
  const int wm = wid >> 1, wn = wid & 1;
#pragma unroll
  for (int i = 0; i < 4; ++i) {
    const int row0 = blockIdx.x * 128 + wm * 64 + i * 16 + ((lane >> 4) << 2);
#pragma unroll
    for (int j = 0; j < 4; ++j) {
      const int col = blockIdx.y * 128 + wn * 64 + j * 16 + (lane & 15);
#pragma unroll
      for (int rr = 0; rr < 4; ++rr) {
        const int row = row0 + rr;
        const float mm = (msk[row] != 0) ? 1.f : 0.f;
        out[(size_t)row * 512 + col] = acc[i][j][rr] * mm;
      }
    }
  }
}

// ---------------- pairwise bias MLP via f16 MFMA -> fp16 bias[b][h][i][j] (round-3 proven) ----------------
__global__ __launch_bounds__(256) void bias_mlp_mfma(
    const float* __restrict__ v, const int* __restrict__ tti,
    const float* __restrict__ W1, const float* __restrict__ b1,
    const float* __restrict__ W2, const float* __restrict__ b2,
    __half* __restrict__ bias) {
  __shared__ float sv[NN][4];
  __shared__ int stt[NN];
  __shared__ _Float16 hbuf[4][16 * 40];
  const int tid = threadIdx.x, lane = tid & 63, w = tid >> 6;
  const int i = blockIdx.x, b = blockIdx.y;
  const int l16 = lane & 15, lg = lane >> 4;
  for (int idx = tid; idx < NN; idx += 256) {
    *(float4*)&sv[idx][0] = *(const float4*)&v[(b * NN + idx) * 4];
    stt[idx] = tti[idx];
  }
  f16x8 w1f[2], w2f;
#pragma unroll
  for (int t = 0; t < 2; ++t)
#pragma unroll
    for (int e = 0; e < 8; ++e) {
      const int kk = lg * 8 + e;
      w1f[t][e] = (kk < 9) ? (_Float16)W1[kk * 32 + t * 16 + l16] : (_Float16)0.f;
    }
#pragma unroll
  for (int e = 0; e < 8; ++e)
    w2f[e] = (l16 < 8) ? (_Float16)W2[(lg * 8 + e) * 8 + l16] : (_Float16)0.f;
  const float b1v0 = b1[l16], b1v1 = b1[16 + l16];
  const float b2v = (l16 < 8) ? b2[l16] : 0.f;
  __syncthreads();
  const float4 vi = *(const float4*)&sv[i][0];
  const int ti = stt[i];
  _Float16* hb = &hbuf[w][0];
  for (int j0 = w * 16; j0 < NN; j0 += 64) {
    const int j = j0 + l16;
    const float4 vj = *(const float4*)&sv[j][0];
    f16x8 af = {0, 0, 0, 0, 0, 0, 0, 0};
    if (lg == 0) {
      af[0] = (_Float16)(vi.x - vj.x); af[1] = (_Float16)(vi.y - vj.y);
      af[2] = (_Float16)(vi.z - vj.z); af[3] = (_Float16)(vi.w - vj.w);
      af[4] = (_Float16)(vi.x * vj.x); af[5] = (_Float16)(vi.y * vj.y);
      af[6] = (_Float16)(vi.z * vj.z); af[7] = (_Float16)(vi.w * vj.w);
    } else if (lg == 1) {
      af[0] = (ti == stt[j]) ? (_Float16)1.f : (_Float16)0.f;
    }
    f32x4 h0 = {b1v0, b1v0, b1v0, b1v0};
    f32x4 h1 = {b1v1, b1v1, b1v1, b1v1};
    h0 = __builtin_amdgcn_mfma_f32_16x16x32_f16(af, w1f[0], h0, 0, 0, 0);
    h1 = __builtin_amdgcn_mfma_f32_16x16x32_f16(af, w1f[1], h1, 0, 0, 0);
#pragma unroll
    for (int r = 0; r < 4; ++r) {
      const int row = lg * 4 + r;
      hb[row * 40 + l16] = (_Float16)fmaxf(h0[r], 0.f);
      hb[row * 40 + 16 + l16] = (_Float16)fmaxf(h1[r], 0.f);
    }
    f16x8 af2 = *(const f16x8*)&hb[l16 * 40 + lg * 8];
    f32x4 o = {b2v, b2v, b2v, b2v};
    o = __builtin_amdgcn_mfma_f32_16x16x32_f16(af2, w2f, o, 0, 0, 0);
    if (l16 < 8) {
      f16x4 pk;
#pragma unroll
      for (int r = 0; r < 4; ++r) pk[r] = (_Float16)o[r];
      *(f16x4*)&bias[((size_t)(b * HH + l16) * NN + i) * NN + j0 + lg * 4] = pk;
    }
  }
}

// ---------------- MFMA flash attention v2: swapped QK^T, vector bias, global V^T ----------------
// block = (it: 64 q-rows, h, b); 4 waves, wave w owns rows it*64+w*16 .. +15.
// S^T = mfma(K,Q): lane l16 = query row i, (lg*4+r) = key row j within jt tile.
// bias: ONE f16x4 global load per jt. No barriers in the j-loop.
__global__ __launch_bounds__(256) void attn_mfma2(
    const unsigned short* __restrict__ q, const unsigned short* __restrict__ k,
    const unsigned short* __restrict__ vt, const __half* __restrict__ bias,
    const int* __restrict__ msk, unsigned short* __restrict__ ao) {
  __shared__ float smask[NN];
  __shared__ unsigned char ps[4][2048];  // per-wave P tile (swz128)
  const int tid = threadIdx.x, lane = tid & 63, w = tid >> 6;
  const int l16 = lane & 15, lg = lane >> 4;
  const int it = blockIdx.x, h_ = blockIdx.y, b_ = blockIdx.z;
  const int bh = b_ * HH + h_;
  const int i_wave = it * 64 + w * 16;
  const unsigned short* qb = q + ((size_t)bh * NN + i_wave) * DHH;
  const unsigned short* kb = k + (size_t)bh * NN * DHH;
  const unsigned short* vtb = vt + (size_t)bh * DHH * NN;
  const __half* brow = bias + ((size_t)bh * NN + (i_wave + l16)) * NN;
  for (int j = tid; j < NN; j += 256) smask[j] = (msk[b_ * NN + j] != 0) ? 0.f : -1e30f;
  __syncthreads();
  // Q as B-fragment: col = l16 = i, k-slice = lg*8 (loads identical to before)
  short8v qf[2];
#pragma unroll
  for (int kc = 0; kc < 2; ++kc)
    qf[kc] = *(const short8v*)&qb[l16 * DHH + kc * 32 + lg * 8];
  f32x4 acc[4];
  const f32x4 z = {0.f, 0.f, 0.f, 0.f};
#pragma unroll
  for (int d = 0; d < 4; ++d) acc[d] = z;
  float mrow = -1e30f, lrow = 0.f;
  unsigned char* psw = &ps[w][0];
  for (int j0 = 0; j0 < NN; j0 += 64) {
    // S^T = K·Q^T (K as A-frag: row=l16 -> key j; loads identical to before)
    f32x4 s[4];
#pragma unroll
    for (int jt = 0; jt < 4; ++jt) {
      const unsigned short* kr = &kb[(j0 + jt * 16 + l16) * DHH + lg * 8];
      short8v kf0 = *(const short8v*)&kr[0];
      short8v kf1 = *(const short8v*)&kr[32];
      f32x4 t = z;
      t = __builtin_amdgcn_mfma_f32_16x16x32_bf16(kf0, qf[0], t, 0, 0, 0);
      t = __builtin_amdgcn_mfma_f32_16x16x32_bf16(kf1, qf[1], t, 0, 0, 0);
      s[jt] = t;
    }
    // scale + bias (vector) + mask (vector LDS)
#pragma unroll
    for (int jt = 0; jt < 4; ++jt) {
      const int jb = j0 + jt * 16 + lg * 4;
      const f16x4 bv = *(const f16x4*)&brow[jb];
      const float4 mk = *(const float4*)&smask[jb];
      s[jt][0] = fmaf(s[jt][0], 0.125f, (float)bv[0]) + mk.x;
      s[jt][1] = fmaf(s[jt][1], 0.125f, (float)bv[1]) + mk.y;
      s[jt][2] = fmaf(s[jt][2], 0.125f, (float)bv[2]) + mk.z;
      s[jt][3] = fmaf(s[jt][3], 0.125f, (float)bv[3]) + mk.w;
    }
    // online softmax for row i=l16 (16 vals/lane, lg-spread -> 2 shuffles)
    float tm = -1e30f;
#pragma unroll
    for (int jt = 0; jt < 4; ++jt)
#pragma unroll
      for (int r = 0; r < 4; ++r) tm = fmaxf(tm, s[jt][r]);
    tm = fmaxf(tm, __shfl_xor(tm, 16));
    tm = fmaxf(tm, __shfl_xor(tm, 32));
    const float mn = fmaxf(mrow, tm);
    const float alpha = __expf(mrow - mn);
    mrow = mn;
    float ts = 0.f;
#pragma unroll
    for (int jt = 0; jt < 4; ++jt)
#pragma unroll
      for (int r = 0; r < 4; ++r) {
        const float p = __expf(s[jt][r] - mn);
        s[jt][r] = p;
        ts += p;
      }
    ts += __shfl_xor(ts, 16);
    ts += __shfl_xor(ts, 32);
    lrow = lrow * alpha + ts;
    // acc rows are i = lg*4+r -> fetch alpha of that row (held at lane l16 = lg*4+r)
    float a4[4];
#pragma unroll
    for (int r = 0; r < 4; ++r) a4[r] = __shfl(alpha, (lg << 2) + r);
#pragma unroll
    for (int d = 0; d < 4; ++d)
#pragma unroll
      for (int r = 0; r < 4; ++r) acc[d][r] *= a4[r];
    // P -> bf16 -> per-wave LDS: lane holds P[i=l16][j=jt*16+lg*4+0..3] -> packed b64
#pragma unroll
    for (int jt = 0; jt < 4; ++jt) {
      ushort4v pk;
#pragma unroll
      for (int r = 0; r < 4; ++r) pk[r] = f2bf(s[jt][r]);
      *(ushort4v*)&psw[swz128(l16, jt * 32 + lg * 8)] = pk;
    }
    // P A-frag (row = l16 = i) — identical read pattern to prior rounds
    short8v pf[2];
#pragma unroll
    for (int kc = 0; kc < 2; ++kc)
      pf[kc] = *(const short8v*)&psw[swz128(l16, kc * 64 + lg * 16)];
    // PV: V^T B-frags straight from global (L2-resident)
#pragma unroll
    for (int d = 0; d < 4; ++d) {
      const unsigned short* vr = &vtb[(size_t)(d * 16 + l16) * NN + j0 + lg * 8];
      short8v vf0 = *(const short8v*)&vr[0];
      short8v vf1 = *(const short8v*)&vr[32];
      acc[d] = __builtin_amdgcn_mfma_f32_16x16x32_bf16(pf[0], vf0, acc[d], 0, 0, 0);
      acc[d] = __builtin_amdgcn_mfma_f32_16x16x32_bf16(pf[1], vf1, acc[d], 0, 0, 0);
    }
  }
  // epilogue: row i = lg*4+r; lrow held at lane l16 = lg*4+r
  float lr4[4];
#pragma unroll
  for (int r = 0; r < 4; ++r) lr4[r] = __shfl(lrow, (lg << 2) + r);
#pragma unroll
  for (int d = 0; d < 4; ++d) {
#pragma unroll
    for (int r = 0; r < 4; ++r) {
      const int row = i_wave + (lg << 2) + r;
      ao[(size_t)(b_ * NN + row) * 512 + h_ * DHH + d * 16 + l16] =
          f2bf(acc[d][r] / lr4[r]);
    }
  }
}

extern "C" void kernel_launch(void* const* d_in, const int* in_sizes, int n_in,
                              void* d_out, int out_size, void* d_ws, size_t ws_size,
                              hipStream_t stream) {
  const float* h     = (const float*)d_in[0];
  const float* v     = (const float*)d_in[1];
  const int*   m     = (const int*)d_in[2];
  const int*   tti   = (const int*)d_in[3];
  const float* W_qkv = (const float*)d_in[4];
  const float* W_out = (const float*)d_in[5];
  const float* W1    = (const float*)d_in[6];
  const float* b1    = (const float*)d_in[7];
  const float* W2    = (const float*)d_in[8];
  const float* b2    = (const float*)d_in[9];
  float* out = (float*)d_out;
  unsigned char* ws = (unsigned char*)d_ws;

  unsigned short* h_bf  = (unsigned short*)(ws + 0);
  unsigned short* q_bf  = (unsigned short*)(ws + 8388608);
  unsigned short* k_bf  = (unsigned short*)(ws + 16777216);
  unsigned short* vt_bf = (unsigned short*)(ws + 25165824);
  unsigned short* ao_bf = (unsigned short*)(ws + 33554432);
  unsigned short* WqT   = (unsigned short*)(ws + 41943040);
  unsigned short* WoT   = (unsigned short*)(ws + 43515904);
  __half* bias          = (__half*)(ws + 44040192);

  cvt_bf<<<4096, 256, 0, stream>>>(h, h_bf, 16 * NN * 512);
  transpose_cvt<<<dim3(16, 48), 256, 0, stream>>>(W_qkv, WqT, 512, 1536);
  transpose_cvt<<<dim3(16, 16), 256, 0, stream>>>(W_out, WoT, 512, 512);
  gemm_qkv<<<dim3(64, 12), 256, 0, stream>>>(h_bf, WqT, q_bf, k_bf, vt_bf);
  bias_mlp_mfma<<<dim3(512, 16), 256, 0, stream>>>(v, tti, W1, b1, W2, b2, bias);
  attn_mfma2<<<dim3(8, 8, 16), 256, 0, stream>>>(q_bf, k_bf, vt_bf, bias, m, ao_bf);
  gemm_out<<<dim3(64, 4), 256, 0, stream>>>(ao_bf, WoT, m, out);
}

// Round 9
// 152.846 us; speedup vs baseline: 1.5260x; 1.3868x over previous
//
#include <hip/hip_runtime.h>
#include <hip/hip_bf16.h>
#include <hip/hip_fp16.h>

// B=16, N=512, D=512, H=8, DH=64, PD=9, HID=32
#define NN 512
#define HH 8
#define DHH 64

typedef __attribute__((ext_vector_type(8))) short short8v;
typedef __attribute__((ext_vector_type(8))) unsigned short ushort8v;
typedef __attribute__((ext_vector_type(4))) unsigned short ushort4v;
typedef __attribute__((ext_vector_type(4))) float f32x4;
typedef __attribute__((ext_vector_type(8))) _Float16 f16x8;
typedef __attribute__((ext_vector_type(4))) _Float16 f16x4;

__device__ __forceinline__ unsigned short f2bf(float x) {
  unsigned u = __builtin_bit_cast(unsigned, x);
  u += 0x7FFFu + ((u >> 16) & 1u);
  return (unsigned short)(u >> 16);
}
__device__ __forceinline__ int swz64(int r, int cb) { return r * 64 + (cb ^ (((r >> 1) & 3) << 4)); }
__device__ __forceinline__ int swz128(int r, int cb) { return r * 128 + (cb ^ ((r & 7) << 4)); }

// ---------------- transpose + cvt: src fp32 [R][C] -> dst bf16 [C][R] ----------------
__global__ __launch_bounds__(256) void transpose_cvt(const float* __restrict__ src,
                                                     unsigned short* __restrict__ dst,
                                                     int R, int C) {
  __shared__ float t[32][33];
  const int r0 = blockIdx.x * 32, c0 = blockIdx.y * 32;
  const int rr = threadIdx.x >> 3, c4 = (threadIdx.x & 7) * 4;
  float4 v = *(const float4*)&src[(size_t)(r0 + rr) * C + c0 + c4];
  t[rr][c4 + 0] = v.x; t[rr][c4 + 1] = v.y; t[rr][c4 + 2] = v.z; t[rr][c4 + 3] = v.w;
  __syncthreads();
  ushort4v o;
#pragma unroll
  for (int e = 0; e < 4; ++e) o[e] = f2bf(t[c4 + e][rr]);
  *(ushort4v*)&dst[(size_t)(c0 + rr) * R + r0 + c4] = o;
}

// ---------------- shared 128x128 bf16 MFMA GEMM body (BK=32, 4 waves) ----------------
// AF32: A operand is fp32 in global, converted to bf16 during LDS staging.
template <bool AF32>
__device__ __forceinline__ void gemm128_body(const void* __restrict__ Ap,
                                             const unsigned short* __restrict__ Bt,
                                             int ldk, int m0, int n0,
                                             f32x4 acc[4][4], unsigned char* smem) {
  const int tid = threadIdx.x, lane = tid & 63, wid = tid >> 6;
  const int wm = wid >> 1, wn = wid & 1;
  int aoff[4], boff[4];
#pragma unroll
  for (int i = 0; i < 4; ++i) {
    aoff[i] = swz64(wm * 64 + i * 16 + (lane & 15), (lane >> 4) * 16);
    boff[i] = 8192 + swz64(wn * 64 + i * 16 + (lane & 15), (lane >> 4) * 16);
  }
  for (int k0 = 0; k0 < ldk; k0 += 32) {
#pragma unroll
    for (int p = 0; p < 2; ++p) {
      const int idx = p * 256 + tid;
      const int r = idx >> 2, cg = idx & 3;
      if constexpr (AF32) {
        const float* A = (const float*)Ap;
        const float* ar = &A[(size_t)(m0 + r) * ldk + k0 + cg * 8];
        float4 f0 = *(const float4*)&ar[0];
        float4 f1 = *(const float4*)&ar[4];
        ushort8v av;
        av[0] = f2bf(f0.x); av[1] = f2bf(f0.y); av[2] = f2bf(f0.z); av[3] = f2bf(f0.w);
        av[4] = f2bf(f1.x); av[5] = f2bf(f1.y); av[6] = f2bf(f1.z); av[7] = f2bf(f1.w);
        *(ushort8v*)&smem[swz64(r, cg * 16)] = av;
      } else {
        const unsigned short* A = (const unsigned short*)Ap;
        ushort8v av = *(const ushort8v*)&A[(size_t)(m0 + r) * ldk + k0 + cg * 8];
        *(ushort8v*)&smem[swz64(r, cg * 16)] = av;
      }
      ushort8v bv = *(const ushort8v*)&Bt[(size_t)(n0 + r) * ldk + k0 + cg * 8];
      *(ushort8v*)&smem[8192 + swz64(r, cg * 16)] = bv;
    }
    __syncthreads();
    short8v a[4], b[4];
#pragma unroll
    for (int i = 0; i < 4; ++i) {
      a[i] = *(const short8v*)&smem[aoff[i]];
      b[i] = *(const short8v*)&smem[boff[i]];
    }
#pragma unroll
    for (int i = 0; i < 4; ++i)
#pragma unroll
      for (int j = 0; j < 4; ++j)
        acc[i][j] = __builtin_amdgcn_mfma_f32_16x16x32_bf16(a[i], b[j], acc[i][j], 0, 0, 0);
    __syncthreads();
  }
}

// ---------------- QKV GEMM: h fp32 [8192][512] @ WqT -> q/k/v bf16 [bh][n][dh] ----------------
__global__ __launch_bounds__(256) void gemm_qkv(const float* __restrict__ A,
                                                const unsigned short* __restrict__ Bt,
                                                unsigned short* __restrict__ q,
                                                unsigned short* __restrict__ k,
                                                unsigned short* __restrict__ v) {
  __shared__ unsigned char smem[16384];
  f32x4 acc[4][4];
  const f32x4 z = {0.f, 0.f, 0.f, 0.f};
#pragma unroll
  for (int i = 0; i < 4; ++i)
#pragma unroll
    for (int j = 0; j < 4; ++j) acc[i][j] = z;
  gemm128_body<true>(A, Bt, 512, blockIdx.x * 128, blockIdx.y * 128, acc, smem);
  const int lane = threadIdx.x & 63, wid = threadIdx.x >> 6;
  const int wm = wid >> 1, wn = wid & 1;
#pragma unroll
  for (int i = 0; i < 4; ++i) {
    const int row0 = blockIdx.x * 128 + wm * 64 + i * 16 + ((lane >> 4) << 2);
#pragma unroll
    for (int j = 0; j < 4; ++j) {
      const int col = blockIdx.y * 128 + wn * 64 + j * 16 + (lane & 15);
      const int part = col >> 9, head = (col >> 6) & 7, dh = col & 63;
      unsigned short* dst = (part == 0) ? q : ((part == 1) ? k : v);
#pragma unroll
      for (int rr = 0; rr < 4; ++rr) {
        const int row = row0 + rr;
        const int b_ = row >> 9, n_ = row & 511;
        dst[(((b_ * HH + head) * NN) + n_) * DHH + dh] = f2bf(acc[i][j][rr]);
      }
    }
  }
}

// ---------------- out GEMM: ao_bf[8192][512] @ WoT -> fp32 out (masked) ----------------
__global__ __launch_bounds__(256) void gemm_out(const unsigned short* __restrict__ A,
                                                const unsigned short* __restrict__ Bt,
                                                const int* __restrict__ msk,
                                                float* __restrict__ out) {
  __shared__ unsigned char smem[16384];
  f32x4 acc[4][4];
  const f32x4 z = {0.f, 0.f, 0.f, 0.f};
#pragma unroll
  for (int i = 0; i < 4; ++i)
#pragma unroll
    for (int j = 0; j < 4; ++j) acc[i][j] = z;
  gemm128_body<false>(A, Bt, 512, blockIdx.x * 128, blockIdx.y * 128, acc, smem);
  const int lane = threadIdx.x & 63, wid = threadIdx.x >> 6;
  const int wm = wid >> 1, wn = wid & 1;
#pragma unroll
  for (int i = 0; i < 4; ++i) {
    const int row0 = blockIdx.x * 128 + wm * 64 + i * 16 + ((lane >> 4) << 2);
#pragma unroll
    for (int j = 0; j < 4; ++j) {
      const int col = blockIdx.y * 128 + wn * 64 + j * 16 + (lane & 15);
#pragma unroll
      for (int rr = 0; rr < 4; ++rr) {
        const int row = row0 + rr;
        const float mm = (msk[row] != 0) ? 1.f : 0.f;
        out[(size_t)row * 512 + col] = acc[i][j][rr] * mm;
      }
    }
  }
}

// ---------------- pairwise bias MLP via f16 MFMA (round-3 math + dbuf hbuf ILP) ----------------
__global__ __launch_bounds__(256) void bias_mlp_mfma(
    const float* __restrict__ v, const int* __restrict__ tti,
    const float* __restrict__ W1, const float* __restrict__ b1,
    const float* __restrict__ W2, const float* __restrict__ b2,
    __half* __restrict__ bias) {
  __shared__ float sv[NN][4];
  __shared__ int stt[NN];
  __shared__ _Float16 hbuf[4][2][16 * 40];  // per-wave, double-buffered
  const int tid = threadIdx.x, lane = tid & 63, w = tid >> 6;
  const int i = blockIdx.x, b = blockIdx.y;
  const int l16 = lane & 15, lg = lane >> 4;
  for (int idx = tid; idx < NN; idx += 256) {
    *(float4*)&sv[idx][0] = *(const float4*)&v[(b * NN + idx) * 4];
    stt[idx] = tti[idx];
  }
  f16x8 w1f[2], w2f;
#pragma unroll
  for (int t = 0; t < 2; ++t)
#pragma unroll
    for (int e = 0; e < 8; ++e) {
      const int kk = lg * 8 + e;
      w1f[t][e] = (kk < 9) ? (_Float16)W1[kk * 32 + t * 16 + l16] : (_Float16)0.f;
    }
#pragma unroll
  for (int e = 0; e < 8; ++e)
    w2f[e] = (l16 < 8) ? (_Float16)W2[(lg * 8 + e) * 8 + l16] : (_Float16)0.f;
  const float b1v0 = b1[l16], b1v1 = b1[16 + l16];
  const float b2v = (l16 < 8) ? b2[l16] : 0.f;
  __syncthreads();
  const float4 vi = *(const float4*)&sv[i][0];
  const int ti = stt[i];
  int bsel = 0;
#pragma unroll 2
  for (int j0 = w * 16; j0 < NN; j0 += 64) {
    _Float16* hb = &hbuf[w][bsel][0];
    const int j = j0 + l16;
    const float4 vj = *(const float4*)&sv[j][0];
    f16x8 af = {0, 0, 0, 0, 0, 0, 0, 0};
    if (lg == 0) {
      af[0] = (_Float16)(vi.x - vj.x); af[1] = (_Float16)(vi.y - vj.y);
      af[2] = (_Float16)(vi.z - vj.z); af[3] = (_Float16)(vi.w - vj.w);
      af[4] = (_Float16)(vi.x * vj.x); af[5] = (_Float16)(vi.y * vj.y);
      af[6] = (_Float16)(vi.z * vj.z); af[7] = (_Float16)(vi.w * vj.w);
    } else if (lg == 1) {
      af[0] = (ti == stt[j]) ? (_Float16)1.f : (_Float16)0.f;
    }
    f32x4 h0 = {b1v0, b1v0, b1v0, b1v0};
    f32x4 h1 = {b1v1, b1v1, b1v1, b1v1};
    h0 = __builtin_amdgcn_mfma_f32_16x16x32_f16(af, w1f[0], h0, 0, 0, 0);
    h1 = __builtin_amdgcn_mfma_f32_16x16x32_f16(af, w1f[1], h1, 0, 0, 0);
#pragma unroll
    for (int r = 0; r < 4; ++r) {
      const int row = lg * 4 + r;
      hb[row * 40 + l16] = (_Float16)fmaxf(h0[r], 0.f);
      hb[row * 40 + 16 + l16] = (_Float16)fmaxf(h1[r], 0.f);
    }
    f16x8 af2 = *(const f16x8*)&hb[l16 * 40 + lg * 8];
    f32x4 o = {b2v, b2v, b2v, b2v};
    o = __builtin_amdgcn_mfma_f32_16x16x32_f16(af2, w2f, o, 0, 0, 0);
    if (l16 < 8) {
      f16x4 pk;
#pragma unroll
      for (int r = 0; r < 4; ++r) pk[r] = (_Float16)o[r];
      *(f16x4*)&bias[((size_t)(b * HH + l16) * NN + i) * NN + j0 + lg * 4] = pk;
    }
    bsel ^= 1;
  }
}

// ---------------- MFMA flash attention (round-3 verbatim) ----------------
// block = (it: 64 q-rows, h, b); 4 waves, wave w owns rows it*64 + w*16 .. +15
__global__ __launch_bounds__(256) void attn_mfma(
    const unsigned short* __restrict__ q, const unsigned short* __restrict__ k,
    const unsigned short* __restrict__ v, const __half* __restrict__ bias,
    const int* __restrict__ msk, unsigned short* __restrict__ ao) {
  __shared__ unsigned char vt[8192];     // V^T tile, [64 dh][128B row] swizzled
  __shared__ unsigned char ps[4][2048];  // per-wave P tile [16][128B] swizzled
  __shared__ float smask[NN];
  const int tid = threadIdx.x, lane = tid & 63, w = tid >> 6;
  const int it = blockIdx.x, h_ = blockIdx.y, b_ = blockIdx.z;
  const int bh = b_ * HH + h_;
  const unsigned short* qb = q + ((size_t)bh * NN + it * 64) * DHH;
  const unsigned short* kb = k + (size_t)bh * NN * DHH;
  const unsigned short* vb = v + (size_t)bh * NN * DHH;
  const __half* bb = bias + (size_t)bh * NN * NN;
  for (int j = tid; j < NN; j += 256) smask[j] = (msk[b_ * NN + j] != 0) ? 0.f : -1e30f;
  short8v qf[2];
#pragma unroll
  for (int kc = 0; kc < 2; ++kc)
    qf[kc] = *(const short8v*)&qb[(w * 16 + (lane & 15)) * DHH + kc * 32 + (lane >> 4) * 8];
  f32x4 acc[4];
  const f32x4 z = {0.f, 0.f, 0.f, 0.f};
#pragma unroll
  for (int d = 0; d < 4; ++d) acc[d] = z;
  float mrow[4], lrow[4];
#pragma unroll
  for (int r = 0; r < 4; ++r) { mrow[r] = -1e30f; lrow[r] = 0.f; }
  __syncthreads();
  const int irow_base = it * 64 + w * 16 + ((lane >> 4) << 2);
  for (int j0 = 0; j0 < NN; j0 += 64) {
#pragma unroll
    for (int p = 0; p < 2; ++p) {
      const int idx = p * 256 + tid;
      const int j = idx & 63, dh0 = (idx >> 6) * 8;
      ushort8v v8 = *(const ushort8v*)&vb[(j0 + j) * DHH + dh0];
#pragma unroll
      for (int e = 0; e < 8; ++e)
        *(unsigned short*)&vt[swz128(dh0 + e, 2 * j)] = v8[e];
    }
    f32x4 s[4];
#pragma unroll
    for (int jt = 0; jt < 4; ++jt) {
      const unsigned short* kr = &kb[(j0 + jt * 16 + (lane & 15)) * DHH + (lane >> 4) * 8];
      short8v kf0 = *(const short8v*)&kr[0];
      short8v kf1 = *(const short8v*)&kr[32];
      f32x4 t = z;
      t = __builtin_amdgcn_mfma_f32_16x16x32_bf16(qf[0], kf0, t, 0, 0, 0);
      t = __builtin_amdgcn_mfma_f32_16x16x32_bf16(qf[1], kf1, t, 0, 0, 0);
      s[jt] = t;
    }
#pragma unroll
    for (int jt = 0; jt < 4; ++jt) {
      const int jcol = j0 + jt * 16 + (lane & 15);
#pragma unroll
      for (int r = 0; r < 4; ++r) {
        const float bv = __half2float(bb[(size_t)(irow_base + r) * NN + jcol]);
        s[jt][r] = fmaf(s[jt][r], 0.125f, bv) + smask[jcol];
      }
    }
    float alpha[4];
#pragma unroll
    for (int r = 0; r < 4; ++r) {
      float tm = fmaxf(fmaxf(s[0][r], s[1][r]), fmaxf(s[2][r], s[3][r]));
      tm = fmaxf(tm, __shfl_xor(tm, 1));
      tm = fmaxf(tm, __shfl_xor(tm, 2));
      tm = fmaxf(tm, __shfl_xor(tm, 4));
      tm = fmaxf(tm, __shfl_xor(tm, 8));
      const float mn = fmaxf(mrow[r], tm);
      alpha[r] = __expf(mrow[r] - mn);
      mrow[r] = mn;
      float ts = 0.f;
#pragma unroll
      for (int jt = 0; jt < 4; ++jt) {
        const float p = __expf(s[jt][r] - mn);
        s[jt][r] = p;
        ts += p;
      }
      ts += __shfl_xor(ts, 1);
      ts += __shfl_xor(ts, 2);
      ts += __shfl_xor(ts, 4);
      ts += __shfl_xor(ts, 8);
      lrow[r] = lrow[r] * alpha[r] + ts;
    }
#pragma unroll
    for (int d = 0; d < 4; ++d)
#pragma unroll
      for (int r = 0; r < 4; ++r) acc[d][r] *= alpha[r];
#pragma unroll
    for (int jt = 0; jt < 4; ++jt)
#pragma unroll
      for (int r = 0; r < 4; ++r)
        *(unsigned short*)&ps[w][swz128(((lane >> 4) << 2) + r, jt * 32 + 2 * (lane & 15))] =
            f2bf(s[jt][r]);
    __syncthreads();
    short8v pf[2];
#pragma unroll
    for (int kc = 0; kc < 2; ++kc)
      pf[kc] = *(const short8v*)&ps[w][swz128(lane & 15, kc * 64 + (lane >> 4) * 16)];
#pragma unroll
    for (int d = 0; d < 4; ++d) {
      short8v vf0 = *(const short8v*)&vt[swz128(d * 16 + (lane & 15), (lane >> 4) * 16)];
      short8v vf1 = *(const short8v*)&vt[swz128(d * 16 + (lane & 15), 64 + (lane >> 4) * 16)];
      acc[d] = __builtin_amdgcn_mfma_f32_16x16x32_bf16(pf[0], vf0, acc[d], 0, 0, 0);
      acc[d] = __builtin_amdgcn_mfma_f32_16x16x32_bf16(pf[1], vf1, acc[d], 0, 0, 0);
    }
    __syncthreads();
  }
#pragma unroll
  for (int d = 0; d < 4; ++d) {
#pragma unroll
    for (int r = 0; r < 4; ++r) {
      const int row = irow_base + r;
      ao[(size_t)(b_ * NN + row) * 512 + h_ * DHH + d * 16 + (lane & 15)] =
          f2bf(acc[d][r] / lrow[r]);
    }
  }
}

extern "C" void kernel_launch(void* const* d_in, const int* in_sizes, int n_in,
                              void* d_out, int out_size, void* d_ws, size_t ws_size,
                              hipStream_t stream) {
  const float* h     = (const float*)d_in[0];
  const float* v     = (const float*)d_in[1];
  const int*   m     = (const int*)d_in[2];
  const int*   tti   = (const int*)d_in[3];
  const float* W_qkv = (const float*)d_in[4];
  const float* W_out = (const float*)d_in[5];
  const float* W1    = (const float*)d_in[6];
  const float* b1    = (const float*)d_in[7];
  const float* W2    = (const float*)d_in[8];
  const float* b2    = (const float*)d_in[9];
  float* out = (float*)d_out;
  unsigned char* ws = (unsigned char*)d_ws;

  unsigned short* q_bf  = (unsigned short*)(ws + 8388608);
  unsigned short* k_bf  = (unsigned short*)(ws + 16777216);
  unsigned short* v_bf  = (unsigned short*)(ws + 25165824);
  unsigned short* ao_bf = (unsigned short*)(ws + 33554432);
  unsigned short* WqT   = (unsigned short*)(ws + 41943040);
  unsigned short* WoT   = (unsigned short*)(ws + 43515904);
  __half* bias          = (__half*)(ws + 44040192);

  transpose_cvt<<<dim3(16, 48), 256, 0, stream>>>(W_qkv, WqT, 512, 1536);
  transpose_cvt<<<dim3(16, 16), 256, 0, stream>>>(W_out, WoT, 512, 512);
  gemm_qkv<<<dim3(64, 12), 256, 0, stream>>>(h, WqT, q_bf, k_bf, v_bf);
  bias_mlp_mfma<<<dim3(512, 16), 256, 0, stream>>>(v, tti, W1, b1, W2, b2, bias);
  attn_mfma<<<dim3(8, 8, 16), 256, 0, stream>>>(q_bf, k_bf, v_bf, bias, m, ao_bf);
  gemm_out<<<dim3(64, 4), 256, 0, stream>>>(ao_bf, WoT, m, out);
}